// Round 7
// baseline (1463.189 us; speedup 1.0000x reference)
//
#include <hip/hip_runtime.h>
#include <hip/hip_bf16.h>
#include <cmath>

#define DD 1536
#define FF 6144

typedef __bf16 bf16_t;
typedef __bf16 bf16x8 __attribute__((ext_vector_type(8)));
typedef __bf16 bf16x4 __attribute__((ext_vector_type(4)));
typedef float  f32x4  __attribute__((ext_vector_type(4)));

#define VM8 asm volatile("s_waitcnt vmcnt(8)" ::: "memory")
#define VM0 asm volatile("s_waitcnt vmcnt(0)" ::: "memory")
#define BAR __builtin_amdgcn_s_barrier()

__device__ __forceinline__ void async_load16(const bf16_t* g, bf16_t* l) {
  __builtin_amdgcn_global_load_lds(
      (const __attribute__((address_space(1))) void*)g,
      (__attribute__((address_space(3))) void*)l, 16, 0, 0);
}

// bijective XCD-aware remap (m204)
__device__ __forceinline__ void xcd_remap(int& bx, int& by) {
  const int gx = gridDim.x, gy = gridDim.y;
  int wg = by * gx + bx;
  const int nwg = gx * gy;
  const int q = nwg >> 3, r = nwg & 7, xcd = wg & 7, o = wg >> 3;
  wg = (xcd < r ? xcd * (q + 1) : r * (q + 1) + (xcd - r) * q) + o;
  bx = wg % gx;
  by = wg / gx;
}

// ---------------- weight fp32 -> bf16 transpose, optional per-K row scale ----------------
__global__ __launch_bounds__(256) void transpose_to_bf16(
    const float* __restrict__ W, bf16_t* __restrict__ Wt, int K, int N,
    const float* __restrict__ s) {
  __shared__ float tile[32][33];
  const int tx = threadIdx.x, ty = threadIdx.y;  // 32 x 8
  const int n0 = blockIdx.x * 32, k0 = blockIdx.y * 32;
#pragma unroll
  for (int i = 0; i < 4; i++)
    tile[ty + 8 * i][tx] = W[(size_t)(k0 + ty + 8 * i) * N + n0 + tx];
  __syncthreads();
  const float sc = (s != nullptr) ? s[k0 + tx] : 1.f;
#pragma unroll
  for (int i = 0; i < 4; i++)
    Wt[(size_t)(n0 + ty + 8 * i) * K + k0 + tx] = (bf16_t)(tile[tx][ty + 8 * i] * sc);
}

// ---------------- reduction helpers ----------------
__device__ __forceinline__ void breduce1(float& a) {
#pragma unroll
  for (int off = 32; off; off >>= 1) a += __shfl_xor(a, off);
  __shared__ float sa[4];
  const int w = threadIdx.x >> 6, ln = threadIdx.x & 63;
  if (ln == 0) sa[w] = a;
  __syncthreads();
  a = (sa[0] + sa[1]) + (sa[2] + sa[3]);
  __syncthreads();
}

__device__ __forceinline__ void breduce2(float& a, float& b) {
#pragma unroll
  for (int off = 32; off; off >>= 1) {
    a += __shfl_xor(a, off);
    b += __shfl_xor(b, off);
  }
  __shared__ float sa[4], sb[4];
  const int w = threadIdx.x >> 6, ln = threadIdx.x & 63;
  if (ln == 0) { sa[w] = a; sb[w] = b; }
  __syncthreads();
  a = (sa[0] + sa[1]) + (sa[2] + sa[3]);
  b = (sb[0] + sb[1]) + (sb[2] + sb[3]);
  __syncthreads();
}

// ---------------- x: shared rms factor -> xr = x*rq (bf16), xb = x (bf16) ----------------
__global__ __launch_bounds__(256) void norm_x2(
    const float* __restrict__ x, bf16_t* __restrict__ xr, bf16_t* __restrict__ xb) {
  const int row = blockIdx.x, t = threadIdx.x;
  const float* p = x + (size_t)row * DD;
  f32x4 v0 = ((const f32x4*)p)[t];
  f32x4 v1 = 0.0f;
  if (t < 128) v1 = ((const f32x4*)p)[256 + t];
  float s2 = 0.f;
#pragma unroll
  for (int e = 0; e < 4; e++) s2 += v0[e] * v0[e];
  if (t < 128) {
#pragma unroll
    for (int e = 0; e < 4; e++) s2 += v1[e] * v1[e];
  }
  breduce1(s2);
  const float rq = rsqrtf(s2 * (1.f / DD) + 1e-7f);
  auto emit = [&](int ci, f32x4 v) {
    bf16x4 orr, ob;
#pragma unroll
    for (int e = 0; e < 4; e++) {
      orr[e] = (bf16_t)(v[e] * rq);
      ob[e] = (bf16_t)v[e];
    }
    const size_t o = (size_t)row * DD + ci * 4;
    *(bf16x4*)(xr + o) = orr;
    *(bf16x4*)(xb + o) = ob;
  };
  emit(t, v0);
  if (t < 128) emit(256 + t, v1);
}

// ---------------- LayerNorm -> bf16 ----------------
__global__ __launch_bounds__(256) void norm_ln(
    const float* __restrict__ x, const float* __restrict__ w,
    const float* __restrict__ bb, bf16_t* __restrict__ o) {
  const int row = blockIdx.x, t = threadIdx.x;
  const float* p = x + (size_t)row * DD;
  f32x4 v0 = ((const f32x4*)p)[t];
  f32x4 v1 = 0.0f;
  if (t < 128) v1 = ((const f32x4*)p)[256 + t];
  float s = 0.f, s2 = 0.f;
#pragma unroll
  for (int e = 0; e < 4; e++) { s += v0[e]; s2 += v0[e] * v0[e]; }
  if (t < 128) {
#pragma unroll
    for (int e = 0; e < 4; e++) { s += v1[e]; s2 += v1[e] * v1[e]; }
  }
  breduce2(s, s2);
  const float mu = s * (1.f / DD);
  const float rln = rsqrtf(s2 * (1.f / DD) - mu * mu + 1e-5f);
  auto emit = [&](int ci, f32x4 v) {
    const int i0 = ci * 4;
    bf16x4 ov;
#pragma unroll
    for (int e = 0; e < 4; e++)
      ov[e] = (bf16_t)((v[e] - mu) * rln * w[i0 + e] + bb[i0 + e]);
    *(bf16x4*)(o + (size_t)row * DD + i0) = ov;
  };
  emit(t, v0);
  if (t < 128) emit(256 + t, v1);
}

// ---------------- text: Tb = raw bf16, Tck = text*rtq (ck_w folded into weight) ----------
__global__ __launch_bounds__(256) void norm_t2(
    const float* __restrict__ te, bf16_t* __restrict__ tb, bf16_t* __restrict__ tck) {
  const int row = blockIdx.x, t = threadIdx.x;
  const float* p = te + (size_t)row * DD;
  f32x4 v0 = ((const f32x4*)p)[t];
  f32x4 v1 = 0.0f;
  if (t < 128) v1 = ((const f32x4*)p)[256 + t];
  float s2 = 0.f;
#pragma unroll
  for (int e = 0; e < 4; e++) s2 += v0[e] * v0[e];
  if (t < 128) {
#pragma unroll
    for (int e = 0; e < 4; e++) s2 += v1[e] * v1[e];
  }
  breduce1(s2);
  const float rq = rsqrtf(s2 * (1.f / DD) + 1e-7f);
  auto emit = [&](int ci, f32x4 v) {
    bf16x4 ob, oc;
#pragma unroll
    for (int e = 0; e < 4; e++) {
      ob[e] = (bf16_t)v[e];
      oc[e] = (bf16_t)(v[e] * rq);
    }
    const size_t o = (size_t)row * DD + ci * 4;
    *(bf16x4*)(tb + o) = ob;
    *(bf16x4*)(tck + o) = oc;
  };
  emit(t, v0);
  if (t < 128) emit(256 + t, v1);
}

// ---------------- in-place bf16 row softmax ----------------
template <int NC>
__global__ __launch_bounds__(256) void softmax_bf16(bf16_t* __restrict__ S) {
  const int t = threadIdx.x;
  bf16_t* sr = S + (size_t)blockIdx.x * NC;
  constexpr int NV = (NC / 8 + 255) / 256;
  float v[NV][8];
  float mx = -3.4e38f;
#pragma unroll
  for (int i = 0; i < NV; i++) {
    const int idx = t + i * 256;
    if (idx * 8 < NC) {
      bf16x8 b = ((const bf16x8*)sr)[idx];
#pragma unroll
      for (int e = 0; e < 8; e++) {
        v[i][e] = (float)b[e];
        mx = fmaxf(mx, v[i][e]);
      }
    }
  }
#pragma unroll
  for (int off = 32; off; off >>= 1) mx = fmaxf(mx, __shfl_xor(mx, off));
  __shared__ float sm[4];
  const int w = t >> 6, ln = t & 63;
  if (ln == 0) sm[w] = mx;
  __syncthreads();
  mx = fmaxf(fmaxf(sm[0], sm[1]), fmaxf(sm[2], sm[3]));
  __syncthreads();
  float sum = 0.f;
#pragma unroll
  for (int i = 0; i < NV; i++) {
    const int idx = t + i * 256;
    if (idx * 8 < NC) {
#pragma unroll
      for (int e = 0; e < 8; e++) {
        v[i][e] = __expf(v[i][e] - mx);
        sum += v[i][e];
      }
    }
  }
#pragma unroll
  for (int off = 32; off; off >>= 1) sum += __shfl_xor(sum, off);
  __shared__ float ss[4];
  if (ln == 0) ss[w] = sum;
  __syncthreads();
  sum = (ss[0] + ss[1]) + (ss[2] + ss[3]);
  const float inv = 1.f / sum;
#pragma unroll
  for (int i = 0; i < NV; i++) {
    const int idx = t + i * 256;
    if (idx * 8 < NC) {
      bf16x8 o;
#pragma unroll
      for (int e = 0; e < 8; e++) o[e] = (bf16_t)(v[i][e] * inv);
      ((bf16x8*)sr)[idx] = o;
    }
  }
}

enum { EPI_BF16 = 0, EPI_F32_SCALE = 1, EPI_ADD_X = 2, EPI_ACC = 3, EPI_GELU = 4, EPI_TRANS = 5, EPI_BF16S = 6 };

// shared epilogue write for one 4-row fragment column
template <int EPI>
__device__ __forceinline__ void epi_frag(
    f32x4 v, int r0, int c, const float* bias, void* Cout, const float* Xres,
    int ldc, float scale, int t_ld, int t_bshift, size_t t_bstride) {
  const float bv = (bias != nullptr) ? bias[c] : 0.f;
  if constexpr (EPI == EPI_BF16) {
    bf16_t* C = (bf16_t*)Cout;
#pragma unroll
    for (int r = 0; r < 4; r++) C[(size_t)(r0 + r) * ldc + c] = (bf16_t)(v[r] + bv);
  } else if constexpr (EPI == EPI_F32_SCALE) {
    float* C = (float*)Cout;
#pragma unroll
    for (int r = 0; r < 4; r++) C[(size_t)(r0 + r) * ldc + c] = v[r] * scale;
  } else if constexpr (EPI == EPI_BF16S) {
    bf16_t* C = (bf16_t*)Cout;
#pragma unroll
    for (int r = 0; r < 4; r++) C[(size_t)(r0 + r) * ldc + c] = (bf16_t)(v[r] * scale);
  } else if constexpr (EPI == EPI_ADD_X) {
    float* C = (float*)Cout;
#pragma unroll
    for (int r = 0; r < 4; r++) {
      const size_t ix = (size_t)(r0 + r) * ldc + c;
      C[ix] = Xres[ix] + v[r] + bv;
    }
  } else if constexpr (EPI == EPI_ACC) {
    float* C = (float*)Cout;
#pragma unroll
    for (int r = 0; r < 4; r++) {
      const size_t ix = (size_t)(r0 + r) * ldc + c;
      C[ix] += v[r] + bv;
    }
  } else if constexpr (EPI == EPI_GELU) {
    bf16_t* C = (bf16_t*)Cout;
#pragma unroll
    for (int r = 0; r < 4; r++) {
      const float h = v[r] + bv;
      C[(size_t)(r0 + r) * ldc + c] = (bf16_t)(0.5f * h * (1.f + erff(h * 0.70710678118654752f)));
    }
  } else {  // EPI_TRANS: batched C^T: out[b][c][n]
    const int b = r0 >> t_bshift;
    const int n = r0 & ((1 << t_bshift) - 1);
    bf16_t* C = (bf16_t*)Cout + (size_t)b * t_bstride + (size_t)c * t_ld + n;
    bf16x4 o;
#pragma unroll
    for (int r = 0; r < 4; r++) o[r] = (bf16_t)(v[r] + bv);
    *(bf16x4*)C = o;
  }
}

// ---------------- gemm_bt: 128x128 tile, 4 waves, BK=32 (proven r2 kernel + batch-B) ------
template <int EPI>
__global__ __launch_bounds__(256) void gemm_bt(
    const bf16_t* __restrict__ A, const bf16_t* __restrict__ B,
    const float* __restrict__ bias, void* __restrict__ Cout,
    const float* __restrict__ Xres,
    int nK, int lda, int ldb, int ldc, float scale,
    int bsh, size_t bstr, int t_ld, int t_bshift, size_t t_bstride) {
  __shared__ __align__(16) bf16_t As[2][128 * 32];
  __shared__ __align__(16) bf16_t Bs[2][128 * 32];
  const int tid = threadIdx.x;
  int bx = blockIdx.x, by = blockIdx.y;
  xcd_remap(bx, by);
  const int m0 = by * 128, n0 = bx * 128;
  const int wave = tid >> 6, lane = tid & 63, l15 = lane & 15, hi = lane >> 4;
  const int wm = wave >> 1, wn = wave & 1;
  const int srow = tid >> 2, scol = (tid & 3) << 3;

  const bf16_t* Bb = bsh ? (B + (size_t)(m0 >> bsh) * bstr) : B;
  const bf16_t* ga = A + (size_t)(m0 + srow) * lda + scol;
  const bf16_t* gb = Bb + (size_t)(n0 + srow) * ldb + scol;
  const int lo = wave * 512;

  f32x4 acc[4][4];
#pragma unroll
  for (int i = 0; i < 4; i++)
#pragma unroll
    for (int j = 0; j < 4; j++) acc[i][j] = 0.0f;

  auto stage = [&](int buf, int kt) {
    const bf16_t* a = ga + (size_t)kt * 32;
    const bf16_t* b = gb + (size_t)kt * 32;
    async_load16(a, &As[buf][lo]);
    async_load16(a + (size_t)64 * lda, &As[buf][2048 + lo]);
    async_load16(b, &Bs[buf][lo]);
    async_load16(b + (size_t)64 * ldb, &Bs[buf][2048 + lo]);
  };

  auto compute = [&](int buf) {
    bf16x8 af[4], bg[4];
#pragma unroll
    for (int i = 0; i < 4; i++)
      af[i] = *(const bf16x8*)&As[buf][(wm * 64 + i * 16 + l15) * 32 + hi * 8];
#pragma unroll
    for (int j = 0; j < 4; j++)
      bg[j] = *(const bf16x8*)&Bs[buf][(wn * 64 + j * 16 + l15) * 32 + hi * 8];
#pragma unroll
    for (int i = 0; i < 4; i++)
#pragma unroll
      for (int j = 0; j < 4; j++)
        acc[i][j] = __builtin_amdgcn_mfma_f32_16x16x32_bf16(af[i], bg[j], acc[i][j], 0, 0, 0);
  };

  stage(0, 0);
  __syncthreads();
  for (int kt = 0; kt < nK; ++kt) {
    if (kt + 1 < nK) stage((kt + 1) & 1, kt + 1);
    compute(kt & 1);
    __syncthreads();
  }

#pragma unroll
  for (int i = 0; i < 4; i++) {
    const int r0 = m0 + wm * 64 + i * 16 + hi * 4;
#pragma unroll
    for (int j = 0; j < 4; j++) {
      const int c = n0 + wn * 64 + j * 16 + l15;
      epi_frag<EPI>(acc[i][j], r0, c, bias, Cout, Xres, ldc, scale, t_ld, t_bshift, t_bstride);
    }
  }
}

// ---------------- gemm8: 256x256 tile, 8 waves, BK=64, deep-prefetch 8-phase ----------
// Slot schedule (iter k, buf=k&1): q0 stages Ah(k+1); q2 stages Bl(k+2); q3 stages
// Bh(k+2)+Al(k+2). WAR-safe: all B[buf] reads complete by q1-end barrier, A[buf] by
// q2-end barrier (MFMA issue implies its ds_reads drained; barrier globalizes).
// vmcnt(8) at q0: the 8 newest in-flight loads are exactly tile k+1's halves, and VMEM
// retires in order, so <=8 outstanding => tile k fully landed. CRITICAL (r6 lesson):
// vmcnt is PER-WAVE — q0's ds_reads must come AFTER the barrier that globalizes the
// drain (VM8; BAR; reads), never before.
template <int EPI>
__global__ __launch_bounds__(512, 2) void gemm8(
    const bf16_t* __restrict__ A, const bf16_t* __restrict__ B,
    const float* __restrict__ bias, void* __restrict__ Cout,
    const float* __restrict__ Xres,
    int nT, int lda, int ldb, int ldc, float scale,
    int bsh, size_t bstr, int t_ld, int t_bshift, size_t t_bstride) {
  __shared__ __align__(16) bf16_t As[2][256 * 64];
  __shared__ __align__(16) bf16_t Bs[2][256 * 64];
  const int tid = threadIdx.x;
  int bx = blockIdx.x, by = blockIdx.y;
  xcd_remap(bx, by);
  const int m0 = by * 256, n0 = bx * 256;
  const int wave = tid >> 6, lane = tid & 63, l15 = lane & 15, hi = lane >> 4;
  const int wm = wave >> 2, wn = wave & 3;  // 2 x 4 waves; per-wave 128x64 output

  // staging: thread covers row tid>>3 (of 64-row group), 16B chunk tid&7, source pre-swizzled
  const int srow = tid >> 3;
  const int scol = ((tid & 7) ^ (srow & 7)) << 3;
  const bf16_t* Bb = bsh ? (B + (size_t)(m0 >> bsh) * bstr) : B;
  const bf16_t* gA = A + (size_t)(m0 + srow) * lda + scol;
  const bf16_t* gB = Bb + (size_t)(n0 + srow) * ldb + scol;
  const int ldst = wave * 512;  // wave-uniform LDS base within 64-row section

  f32x4 acc[8][4];
#pragma unroll
  for (int i = 0; i < 8; i++)
#pragma unroll
    for (int j = 0; j < 4; j++) acc[i][j] = 0.0f;

  // half-stage: tile t, half in {0: rows 0-127, 1: rows 128-255}; 2 gload_lds per thread
  auto stgA = [&](int t, int half) {
    if (t >= nT) return;
    const int buf = t & 1, r0 = half << 7;
    const size_t kof = (size_t)t * 64;
    async_load16(gA + (size_t)r0 * lda + kof, &As[buf][r0 * 64 + ldst]);
    async_load16(gA + (size_t)(r0 + 64) * lda + kof, &As[buf][(r0 + 64) * 64 + ldst]);
  };
  auto stgB = [&](int t, int half) {
    if (t >= nT) return;
    const int buf = t & 1, r0 = half << 7;
    const size_t kof = (size_t)t * 64;
    async_load16(gB + (size_t)r0 * ldb + kof, &Bs[buf][r0 * 64 + ldst]);
    async_load16(gB + (size_t)(r0 + 64) * ldb + kof, &Bs[buf][(r0 + 64) * 64 + ldst]);
  };

  bf16x8 af[4][2], bg[2][2][2];  // af[i][ks] (current mh), bg[nh][j][ks] (both nh cached)
  auto LDA = [&](int buf, int mh) {
#pragma unroll
    for (int i = 0; i < 4; i++) {
      const int r = wm * 128 + (mh * 4 + i) * 16 + l15;
      const int rx = r & 7;
#pragma unroll
      for (int ks = 0; ks < 2; ks++)
        af[i][ks] = *(const bf16x8*)&As[buf][r * 64 + (((hi + 4 * ks) ^ rx) << 3)];
    }
  };
  auto LDB = [&](int buf, int nh) {
#pragma unroll
    for (int j = 0; j < 2; j++) {
      const int r = wn * 64 + (nh * 2 + j) * 16 + l15;
      const int rx = r & 7;
#pragma unroll
      for (int ks = 0; ks < 2; ks++)
        bg[nh][j][ks] = *(const bf16x8*)&Bs[buf][r * 64 + (((hi + 4 * ks) ^ rx) << 3)];
    }
  };
  auto MM = [&](int mh, int nh) {
    __builtin_amdgcn_s_setprio(1);
#pragma unroll
    for (int i = 0; i < 4; i++)
#pragma unroll
      for (int j = 0; j < 2; j++)
#pragma unroll
        for (int ks = 0; ks < 2; ks++)
          acc[mh * 4 + i][nh * 2 + j] = __builtin_amdgcn_mfma_f32_16x16x32_bf16(
              af[i][ks], bg[nh][j][ks], acc[mh * 4 + i][nh * 2 + j], 0, 0, 0);
    __builtin_amdgcn_s_setprio(0);
  };

  // prologue mirrors steady-state issue order: Bl0,Bh0,Al0,Ah0,Bl1,Bh1,Al1
  stgB(0, 0); stgB(0, 1); stgA(0, 0); stgA(0, 1);
  stgB(1, 0); stgB(1, 1); stgA(1, 0);

  for (int k = 0; k < nT; ++k) {
    const int buf = k & 1;
    // q0: stage Ah(k+1); counted wait; BARRIER (globalize per-wave drain); then reads.
    stgA(k + 1, 1);
    if (k + 1 < nT) { VM8; } else { VM0; }
    BAR;
    LDA(buf, 0);
    LDB(buf, 0);
    MM(0, 0);
    BAR;
    // q1: read bg(nh1) (tile-k data, confirmed at q0); MM(0,1). B[buf] fully read after barrier.
    LDB(buf, 1);
    BAR;
    MM(0, 1);
    BAR;
    // q2: stage Bl(k+2) (B[buf] reads done); read af(mh1); MM(1,0). A[buf] fully read after barrier.
    stgB(k + 2, 0);
    LDA(buf, 1);
    BAR;
    MM(1, 0);
    BAR;
    // q3: stage Bh(k+2)+Al(k+2) (A[buf] reads done); MM(1,1) from registers.
    stgB(k + 2, 1);
    stgA(k + 2, 0);
    BAR;
    MM(1, 1);
    BAR;
  }

#pragma unroll
  for (int fi = 0; fi < 8; fi++) {
    const int r0 = m0 + wm * 128 + fi * 16 + hi * 4;
#pragma unroll
    for (int fj = 0; fj < 4; fj++) {
      const int c = n0 + wn * 64 + fj * 16 + l15;
      epi_frag<EPI>(acc[fi][fj], r0, c, bias, Cout, Xres, ldc, scale, t_ld, t_bshift, t_bstride);
    }
  }
}

// ---------------- host ----------------
extern "C" void kernel_launch(void* const* d_in, const int* in_sizes, int n_in,
                              void* d_out, int out_size, void* d_ws, size_t ws_size,
                              hipStream_t stream) {
  (void)in_sizes; (void)n_in; (void)out_size; (void)ws_size;
  const float* x   = (const float*)d_in[0];
  const float* te  = (const float*)d_in[1];
  const float* sqw = (const float*)d_in[2];
  const float* skw = (const float*)d_in[3];
  const float* cqw = (const float*)d_in[4];
  const float* ckw = (const float*)d_in[5];
  const float* lnw = (const float*)d_in[6];
  const float* lnb = (const float*)d_in[7];
  const float* Wq = (const float*)d_in[8];  const float* bq = (const float*)d_in[9];
  const float* Wk = (const float*)d_in[10]; const float* bk = (const float*)d_in[11];
  const float* Wv = (const float*)d_in[12]; const float* bv = (const float*)d_in[13];
  const float* Wo = (const float*)d_in[14]; const float* bo = (const float*)d_in[15];
  const float* CWq = (const float*)d_in[16]; const float* Cbq = (const float*)d_in[17];
  const float* CWk = (const float*)d_in[18]; const float* Cbk = (const float*)d_in[19];
  const float* CWv = (const float*)d_in[20]; const float* Cbv = (const float*)d_in[21];
  const float* CWo = (const float*)d_in[22]; const float* Cbo = (const float*)d_in[23];
  const float* W1 = (const float*)d_in[24]; const float* b1 = (const float*)d_in[25];
  const float* W2 = (const float*)d_in[26]; const float* b2 = (const float*)d_in[27];
  float* out = (float*)d_out;

  // ---- arena (bf16 element offsets); peak ~170 MB ----
  bf16_t* ws = (bf16_t*)d_ws;
  bf16_t* WT0  = ws;                 // 9437184 el (DD*FF)
  bf16_t* WT1  = ws + 9437184;       // 9437184 el
  bf16_t* Cx   = ws + 18874368;      // 12582912 el: xr -> cross-pre
  bf16_t* Tb   = ws + 31457280;      // 1572864
  bf16_t* Tck  = ws + 33030144;      // 1572864
  bf16_t* QK   = ws + 34603008;      // 25165824: xb -> Q|K (ldc 3072) -> PVout -> LNout
  bf16_t* CK   = ws + 47185920;      // 1572864 (upper half of QK region)
  bf16_t* Vt   = ws + 59768832;      // 12582912: V^T -> CV^T -> H(part)
  bf16_t* CQ   = ws + 72351744;      // 12582912: CQ -> H(part)
  bf16_t* S    = ws;                 // 33554432 el overlay during self-attn
  bf16_t* Sc   = ws;                 // 4194304 el overlay (cross scores)
  bf16_t* PVo  = QK;                 // alias
  bf16_t* LNo  = QK;                 // alias
  bf16_t* H    = Vt;                 // 25165824 el (covers Vt+CQ)
  float* biascat = (float*)(ws + 84934656);  // 3072 f32

  const dim3 blk(256), blk8(512), tb(32, 8);
  const float scl = 0.025515518153991442f;  // 1/sqrt(1536)

  auto T = [&](const float* W, bf16_t* Wt, int K, int N, const float* s) {
    transpose_to_bf16<<<dim3(N / 32, K / 32), tb, 0, stream>>>(W, Wt, K, N, s);
  };
  auto g8 = [](int M, int N) { return dim3(N / 256, M / 256); };
  auto g4 = [](int M, int N) { return dim3(N / 128, M / 128); };

  // bias concat bq|bk
  hipMemcpyAsync(biascat, bq, DD * sizeof(float), hipMemcpyDeviceToDevice, stream);
  hipMemcpyAsync(biascat + DD, bk, DD * sizeof(float), hipMemcpyDeviceToDevice, stream);

  // norms for x (shared rms factor; weights folded into transposed W)
  norm_x2<<<8192, blk, 0, stream>>>(x, Cx, QK /*xb*/);

  // V projection (raw x), V^T batched
  T(Wv, WT0, DD, DD, nullptr);
  gemm8<EPI_TRANS><<<g8(8192, DD), blk8, 0, stream>>>(QK /*xb*/, WT0, bv, Vt, nullptr,
      24, DD, DD, 0, 1.f, 0, 0, 4096, 12, (size_t)DD * 4096);

  // merged Q|K projection + CQ projection (norm weights folded)
  T(Wq, WT1, DD, DD, sqw);
  T(Wk, WT1 + 2359296, DD, DD, skw);
  T(CWq, WT1 + 4718592, DD, DD, cqw);
  gemm8<EPI_BF16><<<g8(8192, 3072), blk8, 0, stream>>>(Cx, WT1, biascat, QK, nullptr,
      24, DD, DD, 3072, 1.f, 0, 0, 0, 0, 0);
  gemm8<EPI_BF16><<<g8(8192, DD), blk8, 0, stream>>>(Cx, WT1 + 4718592, Cbq, CQ, nullptr,
      24, DD, DD, DD, 1.f, 0, 0, 0, 0, 0);

  // self-attention, both batches in one dispatch (B selected via m0>>12)
  gemm8<EPI_BF16S><<<g8(8192, 4096), blk8, 0, stream>>>(QK /*Q*/, QK + DD /*K*/, nullptr, S, nullptr,
      24, 3072, 3072, 4096, scl, 12, (size_t)4096 * 3072, 0, 0, 0);
  softmax_bf16<4096><<<8192, blk, 0, stream>>>(S);
  gemm8<EPI_BF16><<<g8(8192, DD), blk8, 0, stream>>>(S, Vt, nullptr, PVo, nullptr,
      64, 4096, 4096, DD, 1.f, 12, (size_t)DD * 4096, 0, 0, 0);
  T(Wo, WT0, DD, DD, nullptr);
  gemm8<EPI_ADD_X><<<g8(8192, DD), blk8, 0, stream>>>(PVo, WT0, bo, out, x,
      24, DD, DD, DD, 1.f, 0, 0, 0, 0, 0);

  // cross-attention
  norm_t2<<<1024, blk, 0, stream>>>(te, Tb, Tck);
  T(CWk, WT1, DD, DD, ckw);
  gemm_bt<EPI_BF16><<<g4(1024, DD), blk, 0, stream>>>(Tck, WT1, Cbk, CK, nullptr,
      48, DD, DD, DD, 1.f, 0, 0, 0, 0, 0);
  T(CWv, WT0, DD, DD, nullptr);
  gemm_bt<EPI_TRANS><<<g4(1024, DD), blk, 0, stream>>>(Tb, WT0, Cbv, Vt, nullptr,
      48, DD, DD, 0, 1.f, 0, 0, 512, 9, (size_t)DD * 512);
  gemm_bt<EPI_BF16S><<<g4(8192, 512), blk, 0, stream>>>(CQ, CK, nullptr, Sc, nullptr,
      48, DD, DD, 512, scl, 12, (size_t)512 * DD, 0, 0, 0);
  softmax_bf16<512><<<8192, blk, 0, stream>>>(Sc);
  gemm8<EPI_BF16><<<g8(8192, DD), blk8, 0, stream>>>(Sc, Vt, nullptr, Cx, nullptr,
      8, 512, 512, DD, 1.f, 12, (size_t)DD * 512, 0, 0, 0);
  T(CWo, WT1, DD, DD, nullptr);
  gemm8<EPI_ACC><<<g8(8192, DD), blk8, 0, stream>>>(Cx, WT1, Cbo, out, nullptr,
      24, DD, DD, DD, 1.f, 0, 0, 0, 0, 0);

  // FFN: LN -> W1(+gelu) in 2 column chunks of 3072 -> W2 acc
  norm_ln<<<8192, blk, 0, stream>>>(x, lnw, lnb, LNo);
  T(W1, WT0, DD, FF, nullptr);
  T(W2, WT1, FF, DD, nullptr);
  for (int c = 0; c < 2; c++) {
    gemm8<EPI_GELU><<<g8(8192, 3072), blk8, 0, stream>>>(LNo, WT0 + (size_t)c * 4718592,
        b1 + c * 3072, H, nullptr, 24, DD, DD, 3072, 1.f, 0, 0, 0, 0, 0);
    gemm8<EPI_ACC><<<g8(8192, DD), blk8, 0, stream>>>(H, WT1 + c * 3072,
        (c == 0) ? b2 : nullptr, out, nullptr, 48, 3072, FF, DD, 1.f, 0, 0, 0, 0, 0);
  }
}

// Round 8
// 1346.074 us; speedup vs baseline: 1.0870x; 1.0870x over previous
//
#include <hip/hip_runtime.h>
#include <hip/hip_bf16.h>
#include <cmath>

#define DD 1536
#define FF 6144

typedef __bf16 bf16_t;
typedef __bf16 bf16x8 __attribute__((ext_vector_type(8)));
typedef __bf16 bf16x4 __attribute__((ext_vector_type(4)));
typedef float  f32x4  __attribute__((ext_vector_type(4)));

#define VM6 asm volatile("s_waitcnt vmcnt(6)" ::: "memory")
#define VM0 asm volatile("s_waitcnt vmcnt(0)" ::: "memory")
#define BAR __builtin_amdgcn_s_barrier()

__device__ __forceinline__ void async_load16(const bf16_t* g, bf16_t* l) {
  __builtin_amdgcn_global_load_lds(
      (const __attribute__((address_space(1))) void*)g,
      (__attribute__((address_space(3))) void*)l, 16, 0, 0);
}

// bijective XCD-aware remap (m204)
__device__ __forceinline__ void xcd_remap(int& bx, int& by) {
  const int gx = gridDim.x, gy = gridDim.y;
  int wg = by * gx + bx;
  const int nwg = gx * gy;
  const int q = nwg >> 3, r = nwg & 7, xcd = wg & 7, o = wg >> 3;
  wg = (xcd < r ? xcd * (q + 1) : r * (q + 1) + (xcd - r) * q) + o;
  bx = wg % gx;
  by = wg / gx;
}

// ---------------- weight fp32 -> bf16 transpose; optional per-K scale; output row stride ldt
__global__ __launch_bounds__(256) void transpose_to_bf16(
    const float* __restrict__ W, bf16_t* __restrict__ Wt, int K, int N,
    const float* __restrict__ s, int ldt) {
  __shared__ float tile[32][33];
  const int tx = threadIdx.x, ty = threadIdx.y;  // 32 x 8
  const int n0 = blockIdx.x * 32, k0 = blockIdx.y * 32;
#pragma unroll
  for (int i = 0; i < 4; i++)
    tile[ty + 8 * i][tx] = W[(size_t)(k0 + ty + 8 * i) * N + n0 + tx];
  __syncthreads();
  const float sc = (s != nullptr) ? s[k0 + tx] : 1.f;
#pragma unroll
  for (int i = 0; i < 4; i++)
    Wt[(size_t)(n0 + ty + 8 * i) * ldt + k0 + tx] = (bf16_t)(tile[tx][ty + 8 * i] * sc);
}

// ---------------- biasm = a + b (1536) ----------------
__global__ __launch_bounds__(256) void bias_add2(
    const float* __restrict__ a, const float* __restrict__ b, float* __restrict__ o, int n) {
  const int i = blockIdx.x * 256 + threadIdx.x;
  if (i < n) o[i] = a[i] + b[i];
}

// ---------------- reduction helpers ----------------
__device__ __forceinline__ void breduce1(float& a) {
#pragma unroll
  for (int off = 32; off; off >>= 1) a += __shfl_xor(a, off);
  __shared__ float sa[4];
  const int w = threadIdx.x >> 6, ln = threadIdx.x & 63;
  if (ln == 0) sa[w] = a;
  __syncthreads();
  a = (sa[0] + sa[1]) + (sa[2] + sa[3]);
  __syncthreads();
}

__device__ __forceinline__ void breduce2(float& a, float& b) {
#pragma unroll
  for (int off = 32; off; off >>= 1) {
    a += __shfl_xor(a, off);
    b += __shfl_xor(b, off);
  }
  __shared__ float sa[4], sb[4];
  const int w = threadIdx.x >> 6, ln = threadIdx.x & 63;
  if (ln == 0) { sa[w] = a; sb[w] = b; }
  __syncthreads();
  a = (sa[0] + sa[1]) + (sa[2] + sa[3]);
  b = (sb[0] + sb[1]) + (sb[2] + sb[3]);
  __syncthreads();
}

// ---------------- x: shared rms factor -> xr = x*rq (bf16), xb = x (bf16) ----------------
__global__ __launch_bounds__(256) void norm_x2(
    const float* __restrict__ x, bf16_t* __restrict__ xr, bf16_t* __restrict__ xb) {
  const int row = blockIdx.x, t = threadIdx.x;
  const float* p = x + (size_t)row * DD;
  f32x4 v0 = ((const f32x4*)p)[t];
  f32x4 v1 = 0.0f;
  if (t < 128) v1 = ((const f32x4*)p)[256 + t];
  float s2 = 0.f;
#pragma unroll
  for (int e = 0; e < 4; e++) s2 += v0[e] * v0[e];
  if (t < 128) {
#pragma unroll
    for (int e = 0; e < 4; e++) s2 += v1[e] * v1[e];
  }
  breduce1(s2);
  const float rq = rsqrtf(s2 * (1.f / DD) + 1e-7f);
  auto emit = [&](int ci, f32x4 v) {
    bf16x4 orr, ob;
#pragma unroll
    for (int e = 0; e < 4; e++) {
      orr[e] = (bf16_t)(v[e] * rq);
      ob[e] = (bf16_t)v[e];
    }
    const size_t o = (size_t)row * DD + ci * 4;
    *(bf16x4*)(xr + o) = orr;
    *(bf16x4*)(xb + o) = ob;
  };
  emit(t, v0);
  if (t < 128) emit(256 + t, v1);
}

// ---------------- LayerNorm -> bf16 ----------------
__global__ __launch_bounds__(256) void norm_ln(
    const float* __restrict__ x, const float* __restrict__ w,
    const float* __restrict__ bb, bf16_t* __restrict__ o) {
  const int row = blockIdx.x, t = threadIdx.x;
  const float* p = x + (size_t)row * DD;
  f32x4 v0 = ((const f32x4*)p)[t];
  f32x4 v1 = 0.0f;
  if (t < 128) v1 = ((const f32x4*)p)[256 + t];
  float s = 0.f, s2 = 0.f;
#pragma unroll
  for (int e = 0; e < 4; e++) { s += v0[e]; s2 += v0[e] * v0[e]; }
  if (t < 128) {
#pragma unroll
    for (int e = 0; e < 4; e++) { s += v1[e]; s2 += v1[e] * v1[e]; }
  }
  breduce2(s, s2);
  const float mu = s * (1.f / DD);
  const float rln = rsqrtf(s2 * (1.f / DD) - mu * mu + 1e-5f);
  auto emit = [&](int ci, f32x4 v) {
    const int i0 = ci * 4;
    bf16x4 ov;
#pragma unroll
    for (int e = 0; e < 4; e++)
      ov[e] = (bf16_t)((v[e] - mu) * rln * w[i0 + e] + bb[i0 + e]);
    *(bf16x4*)(o + (size_t)row * DD + i0) = ov;
  };
  emit(t, v0);
  if (t < 128) emit(256 + t, v1);
}

// ---------------- text: Tb = raw bf16, Tck = text*rtq ----------
__global__ __launch_bounds__(256) void norm_t2(
    const float* __restrict__ te, bf16_t* __restrict__ tb, bf16_t* __restrict__ tck) {
  const int row = blockIdx.x, t = threadIdx.x;
  const float* p = te + (size_t)row * DD;
  f32x4 v0 = ((const f32x4*)p)[t];
  f32x4 v1 = 0.0f;
  if (t < 128) v1 = ((const f32x4*)p)[256 + t];
  float s2 = 0.f;
#pragma unroll
  for (int e = 0; e < 4; e++) s2 += v0[e] * v0[e];
  if (t < 128) {
#pragma unroll
    for (int e = 0; e < 4; e++) s2 += v1[e] * v1[e];
  }
  breduce1(s2);
  const float rq = rsqrtf(s2 * (1.f / DD) + 1e-7f);
  auto emit = [&](int ci, f32x4 v) {
    bf16x4 ob, oc;
#pragma unroll
    for (int e = 0; e < 4; e++) {
      ob[e] = (bf16_t)v[e];
      oc[e] = (bf16_t)(v[e] * rq);
    }
    const size_t o = (size_t)row * DD + ci * 4;
    *(bf16x4*)(tb + o) = ob;
    *(bf16x4*)(tck + o) = oc;
  };
  emit(t, v0);
  if (t < 128) emit(256 + t, v1);
}

// ---------------- in-place bf16 row softmax ----------------
template <int NC>
__global__ __launch_bounds__(256) void softmax_bf16(bf16_t* __restrict__ S) {
  const int t = threadIdx.x;
  bf16_t* sr = S + (size_t)blockIdx.x * NC;
  constexpr int NV = (NC / 8 + 255) / 256;
  float v[NV][8];
  float mx = -3.4e38f;
#pragma unroll
  for (int i = 0; i < NV; i++) {
    const int idx = t + i * 256;
    if (idx * 8 < NC) {
      bf16x8 b = ((const bf16x8*)sr)[idx];
#pragma unroll
      for (int e = 0; e < 8; e++) {
        v[i][e] = (float)b[e];
        mx = fmaxf(mx, v[i][e]);
      }
    }
  }
#pragma unroll
  for (int off = 32; off; off >>= 1) mx = fmaxf(mx, __shfl_xor(mx, off));
  __shared__ float sm[4];
  const int w = t >> 6, ln = t & 63;
  if (ln == 0) sm[w] = mx;
  __syncthreads();
  mx = fmaxf(fmaxf(sm[0], sm[1]), fmaxf(sm[2], sm[3]));
  __syncthreads();
  float sum = 0.f;
#pragma unroll
  for (int i = 0; i < NV; i++) {
    const int idx = t + i * 256;
    if (idx * 8 < NC) {
#pragma unroll
      for (int e = 0; e < 8; e++) {
        v[i][e] = __expf(v[i][e] - mx);
        sum += v[i][e];
      }
    }
  }
#pragma unroll
  for (int off = 32; off; off >>= 1) sum += __shfl_xor(sum, off);
  __shared__ float ss[4];
  if (ln == 0) ss[w] = sum;
  __syncthreads();
  sum = (ss[0] + ss[1]) + (ss[2] + ss[3]);
  const float inv = 1.f / sum;
#pragma unroll
  for (int i = 0; i < NV; i++) {
    const int idx = t + i * 256;
    if (idx * 8 < NC) {
      bf16x8 o;
#pragma unroll
      for (int e = 0; e < 8; e++) o[e] = (bf16_t)(v[i][e] * inv);
      ((bf16x8*)sr)[idx] = o;
    }
  }
}

enum { EPI_BF16 = 0, EPI_F32_SCALE = 1, EPI_ADD_X = 2, EPI_ACC = 3, EPI_GELU = 4, EPI_TRANS = 5, EPI_BF16S = 6 };

template <int EPI>
__device__ __forceinline__ void epi_frag(
    f32x4 v, int r0, int c, const float* bias, void* Cout, const float* Xres,
    int ldc, float scale, int t_ld, int t_bshift, size_t t_bstride) {
  const float bv = (bias != nullptr) ? bias[c] : 0.f;
  if constexpr (EPI == EPI_BF16) {
    bf16_t* C = (bf16_t*)Cout;
#pragma unroll
    for (int r = 0; r < 4; r++) C[(size_t)(r0 + r) * ldc + c] = (bf16_t)(v[r] + bv);
  } else if constexpr (EPI == EPI_F32_SCALE) {
    float* C = (float*)Cout;
#pragma unroll
    for (int r = 0; r < 4; r++) C[(size_t)(r0 + r) * ldc + c] = v[r] * scale;
  } else if constexpr (EPI == EPI_BF16S) {
    bf16_t* C = (bf16_t*)Cout;
#pragma unroll
    for (int r = 0; r < 4; r++) C[(size_t)(r0 + r) * ldc + c] = (bf16_t)(v[r] * scale);
  } else if constexpr (EPI == EPI_ADD_X) {
    float* C = (float*)Cout;
#pragma unroll
    for (int r = 0; r < 4; r++) {
      const size_t ix = (size_t)(r0 + r) * ldc + c;
      C[ix] = Xres[ix] + v[r] + bv;
    }
  } else if constexpr (EPI == EPI_ACC) {
    float* C = (float*)Cout;
#pragma unroll
    for (int r = 0; r < 4; r++) {
      const size_t ix = (size_t)(r0 + r) * ldc + c;
      C[ix] += v[r] + bv;
    }
  } else if constexpr (EPI == EPI_GELU) {
    bf16_t* C = (bf16_t*)Cout;
#pragma unroll
    for (int r = 0; r < 4; r++) {
      const float h = v[r] + bv;
      C[(size_t)(r0 + r) * ldc + c] = (bf16_t)(0.5f * h * (1.f + erff(h * 0.70710678118654752f)));
    }
  } else {  // EPI_TRANS: batched C^T: out[b][c][n]
    const int b = r0 >> t_bshift;
    const int n = r0 & ((1 << t_bshift) - 1);
    bf16_t* C = (bf16_t*)Cout + (size_t)b * t_bstride + (size_t)c * t_ld + n;
    bf16x4 o;
#pragma unroll
    for (int r = 0; r < 4; r++) o[r] = (bf16_t)(v[r] + bv);
    *(bf16x4*)C = o;
  }
}

// ---------------- gemm_bt: 128x128 tile, 4 waves, BK=32 (proven r2 kernel + batch-B) ------
template <int EPI>
__global__ __launch_bounds__(256) void gemm_bt(
    const bf16_t* __restrict__ A, const bf16_t* __restrict__ B,
    const float* __restrict__ bias, void* __restrict__ Cout,
    const float* __restrict__ Xres,
    int nK, int lda, int ldb, int ldc, float scale,
    int bsh, size_t bstr, int t_ld, int t_bshift, size_t t_bstride) {
  __shared__ __align__(16) bf16_t As[2][128 * 32];
  __shared__ __align__(16) bf16_t Bs[2][128 * 32];
  const int tid = threadIdx.x;
  int bx = blockIdx.x, by = blockIdx.y;
  xcd_remap(bx, by);
  const int m0 = by * 128, n0 = bx * 128;
  const int wave = tid >> 6, lane = tid & 63, l15 = lane & 15, hi = lane >> 4;
  const int wm = wave >> 1, wn = wave & 1;
  const int srow = tid >> 2, scol = (tid & 3) << 3;

  const bf16_t* Bb = bsh ? (B + (size_t)(m0 >> bsh) * bstr) : B;
  const bf16_t* ga = A + (size_t)(m0 + srow) * lda + scol;
  const bf16_t* gb = Bb + (size_t)(n0 + srow) * ldb + scol;
  const int lo = wave * 512;

  f32x4 acc[4][4];
#pragma unroll
  for (int i = 0; i < 4; i++)
#pragma unroll
    for (int j = 0; j < 4; j++) acc[i][j] = 0.0f;

  auto stage = [&](int buf, int kt) {
    const bf16_t* a = ga + (size_t)kt * 32;
    const bf16_t* b = gb + (size_t)kt * 32;
    async_load16(a, &As[buf][lo]);
    async_load16(a + (size_t)64 * lda, &As[buf][2048 + lo]);
    async_load16(b, &Bs[buf][lo]);
    async_load16(b + (size_t)64 * ldb, &Bs[buf][2048 + lo]);
  };

  auto compute = [&](int buf) {
    bf16x8 af[4], bg[4];
#pragma unroll
    for (int i = 0; i < 4; i++)
      af[i] = *(const bf16x8*)&As[buf][(wm * 64 + i * 16 + l15) * 32 + hi * 8];
#pragma unroll
    for (int j = 0; j < 4; j++)
      bg[j] = *(const bf16x8*)&Bs[buf][(wn * 64 + j * 16 + l15) * 32 + hi * 8];
#pragma unroll
    for (int i = 0; i < 4; i++)
#pragma unroll
      for (int j = 0; j < 4; j++)
        acc[i][j] = __builtin_amdgcn_mfma_f32_16x16x32_bf16(af[i], bg[j], acc[i][j], 0, 0, 0);
  };

  stage(0, 0);
  __syncthreads();
  for (int kt = 0; kt < nK; ++kt) {
    if (kt + 1 < nK) stage((kt + 1) & 1, kt + 1);
    compute(kt & 1);
    __syncthreads();
  }

#pragma unroll
  for (int i = 0; i < 4; i++) {
    const int r0 = m0 + wm * 64 + i * 16 + hi * 4;
#pragma unroll
    for (int j = 0; j < 4; j++) {
      const int c = n0 + wn * 64 + j * 16 + l15;
      epi_frag<EPI>(acc[i][j], r0, c, bias, Cout, Xres, ldc, scale, t_ld, t_bshift, t_bstride);
    }
  }
}

// ---------------- gemm8: 256x256 tile, 8 waves, BK=64, reads-ahead 8-phase ----------
// RAW: tile k's data is confirmed at q3(k-1)'s {VM6; BAR} — the 6 newest in-flight loads
// there are exactly {Bl,Bh,Al}(k+2)... i.e. everything up through Ah(k+1) drained, so tile
// k+1 is confirmed one full phase before its q0 reads (m201 pattern: reads follow an
// EARLIER confirming barrier; r6 lesson: vmcnt is per-wave, barrier globalizes).
// Tail: when k+2 >= nT the skipped stages break the count -> VM0 instead (conservative).
// WAR: B[buf] reads drain by q1-close (MM(0,1) consumed), A[buf] by q2-close -> staging
// Bl(k+2)@q2, Bh/Al(k+2)@q3, Ah(k+1)@q0 all land after the respective barriers.
template <int EPI>
__global__ __launch_bounds__(512, 2) void gemm8(
    const bf16_t* __restrict__ A, const bf16_t* __restrict__ B,
    const float* __restrict__ bias, void* __restrict__ Cout,
    const float* __restrict__ Xres,
    int nT, int lda, int ldb, int ldc, float scale,
    int bsh, size_t bstr, int t_ld, int t_bshift, size_t t_bstride) {
  __shared__ __align__(16) bf16_t As[2][256 * 64];
  __shared__ __align__(16) bf16_t Bs[2][256 * 64];
  const int tid = threadIdx.x;
  int bx = blockIdx.x, by = blockIdx.y;
  xcd_remap(bx, by);
  const int m0 = by * 256, n0 = bx * 256;
  const int wave = tid >> 6, lane = tid & 63, l15 = lane & 15, hi = lane >> 4;
  const int wm = wave >> 2, wn = wave & 3;  // 2 x 4 waves; per-wave 128x64 output

  const int srow = tid >> 3;
  const int scol = ((tid & 7) ^ (srow & 7)) << 3;
  const bf16_t* Bb = bsh ? (B + (size_t)(m0 >> bsh) * bstr) : B;
  const bf16_t* gA = A + (size_t)(m0 + srow) * lda + scol;
  const bf16_t* gB = Bb + (size_t)(n0 + srow) * ldb + scol;
  const int ldst = wave * 512;

  f32x4 acc[8][4];
#pragma unroll
  for (int i = 0; i < 8; i++)
#pragma unroll
    for (int j = 0; j < 4; j++) acc[i][j] = 0.0f;

  auto stgA = [&](int t, int half) {
    if (t >= nT) return;
    const int buf = t & 1, r0 = half << 7;
    const size_t kof = (size_t)t * 64;
    async_load16(gA + (size_t)r0 * lda + kof, &As[buf][r0 * 64 + ldst]);
    async_load16(gA + (size_t)(r0 + 64) * lda + kof, &As[buf][(r0 + 64) * 64 + ldst]);
  };
  auto stgB = [&](int t, int half) {
    if (t >= nT) return;
    const int buf = t & 1, r0 = half << 7;
    const size_t kof = (size_t)t * 64;
    async_load16(gB + (size_t)r0 * ldb + kof, &Bs[buf][r0 * 64 + ldst]);
    async_load16(gB + (size_t)(r0 + 64) * ldb + kof, &Bs[buf][(r0 + 64) * 64 + ldst]);
  };

  bf16x8 af[4][2], bg[2][2][2];
  auto LDA = [&](int buf, int mh) {
#pragma unroll
    for (int i = 0; i < 4; i++) {
      const int r = wm * 128 + (mh * 4 + i) * 16 + l15;
      const int rx = r & 7;
#pragma unroll
      for (int ks = 0; ks < 2; ks++)
        af[i][ks] = *(const bf16x8*)&As[buf][r * 64 + (((hi + 4 * ks) ^ rx) << 3)];
    }
  };
  auto LDB = [&](int buf, int nh) {
#pragma unroll
    for (int j = 0; j < 2; j++) {
      const int r = wn * 64 + (nh * 2 + j) * 16 + l15;
      const int rx = r & 7;
#pragma unroll
      for (int ks = 0; ks < 2; ks++)
        bg[nh][j][ks] = *(const bf16x8*)&Bs[buf][r * 64 + (((hi + 4 * ks) ^ rx) << 3)];
    }
  };
  auto MM = [&](int mh, int nh) {
    __builtin_amdgcn_s_setprio(1);
#pragma unroll
    for (int i = 0; i < 4; i++)
#pragma unroll
      for (int j = 0; j < 2; j++)
#pragma unroll
        for (int ks = 0; ks < 2; ks++)
          acc[mh * 4 + i][nh * 2 + j] = __builtin_amdgcn_mfma_f32_16x16x32_bf16(
              af[i][ks], bg[nh][j][ks], acc[mh * 4 + i][nh * 2 + j], 0, 0, 0);
    __builtin_amdgcn_s_setprio(0);
  };

  // prologue: tile0 fully + tile1 {Bl,Bh,Al}; confirm tile 0 (6 newer loads in flight)
  stgB(0, 0); stgB(0, 1); stgA(0, 0); stgA(0, 1);
  stgB(1, 0); stgB(1, 1); stgA(1, 0);
  if (nT > 1) { VM6; } else { VM0; }
  BAR;

  for (int k = 0; k < nT; ++k) {
    const int buf = k & 1;
    // q0: stage Ah(k+1); reads (tile k, confirmed last iter) BEFORE barrier -> latency hides
    stgA(k + 1, 1);
    LDA(buf, 0);
    LDB(buf, 0);
    BAR;
    MM(0, 0);
    BAR;
    // q1: read bg(nh1); B[buf] fully read after this phase
    LDB(buf, 1);
    BAR;
    MM(0, 1);
    BAR;
    // q2: stage Bl(k+2) (B[buf] reads drained); read af(mh1); A[buf] fully read after this phase
    stgB(k + 2, 0);
    LDA(buf, 1);
    BAR;
    MM(1, 0);
    BAR;
    // q3: stage Bh,Al(k+2); confirm tile k+1 (counted; VM0 on tail where stages were skipped)
    stgB(k + 2, 1);
    stgA(k + 2, 0);
    if (k + 2 < nT) { VM6; } else { VM0; }
    BAR;
    MM(1, 1);
    BAR;
  }

#pragma unroll
  for (int fi = 0; fi < 8; fi++) {
    const int r0 = m0 + wm * 128 + fi * 16 + hi * 4;
#pragma unroll
    for (int fj = 0; fj < 4; fj++) {
      const int c = n0 + wn * 64 + fj * 16 + l15;
      epi_frag<EPI>(acc[fi][fj], r0, c, bias, Cout, Xres, ldc, scale, t_ld, t_bshift, t_bstride);
    }
  }
}

// ---------------- host ----------------
extern "C" void kernel_launch(void* const* d_in, const int* in_sizes, int n_in,
                              void* d_out, int out_size, void* d_ws, size_t ws_size,
                              hipStream_t stream) {
  (void)in_sizes; (void)n_in; (void)out_size; (void)ws_size;
  const float* x   = (const float*)d_in[0];
  const float* te  = (const float*)d_in[1];
  const float* sqw = (const float*)d_in[2];
  const float* skw = (const float*)d_in[3];
  const float* cqw = (const float*)d_in[4];
  const float* ckw = (const float*)d_in[5];
  const float* lnw = (const float*)d_in[6];
  const float* lnb = (const float*)d_in[7];
  const float* Wq = (const float*)d_in[8];  const float* bq = (const float*)d_in[9];
  const float* Wk = (const float*)d_in[10]; const float* bk = (const float*)d_in[11];
  const float* Wv = (const float*)d_in[12]; const float* bv = (const float*)d_in[13];
  const float* Wo = (const float*)d_in[14]; const float* bo = (const float*)d_in[15];
  const float* CWq = (const float*)d_in[16]; const float* Cbq = (const float*)d_in[17];
  const float* CWk = (const float*)d_in[18]; const float* Cbk = (const float*)d_in[19];
  const float* CWv = (const float*)d_in[20]; const float* Cbv = (const float*)d_in[21];
  const float* CWo = (const float*)d_in[22]; const float* Cbo = (const float*)d_in[23];
  const float* W1 = (const float*)d_in[24]; const float* b1 = (const float*)d_in[25];
  const float* W2 = (const float*)d_in[26]; const float* b2 = (const float*)d_in[27];
  float* out = (float*)d_out;

  // ---- arena (bf16 el offsets); peak ~170 MB ----
  bf16_t* ws = (bf16_t*)d_ws;
  bf16_t* R0 = ws;                  // 9437184: Wv^T -> {CK,CVt,Sc} -> W1^T
  bf16_t* R1 = ws + 9437184;        // 9437184: Wq|Wk|CWq^T -> CWk/CWv^T -> WTm -> W2^T
  bf16_t* R2 = ws + 18874368;       // 12582912: xr -> LNo
  bf16_t* Tb  = ws + 31457280;      // 1572864
  bf16_t* Tck = ws + 33030144;      // 1572864
  bf16_t* R4 = ws + 34603008;       // 25165824: xb -> Q|K(ldc3072) -> concat APre|CPre -> H[0:..]
  bf16_t* R5 = ws + 59768832;       // 12582912: V^T -> H mid
  bf16_t* R6 = ws + 72351744;       // 12582912: CQ -> H end
  bf16_t* S  = ws;                  // 33554432 overlay (self-attn scores), over R0,R1,R2,Tb+
  float* biascat = (float*)(ws + 84934656);  // 3072 f32
  float* biasm   = (float*)(ws + 84940800);  // 1536 f32
  bf16_t* CK  = R0;                 // 1572864
  bf16_t* CVt = R0 + 1572864;       // 1572864
  bf16_t* Sc  = R0 + 3145728;       // 4194304 (8192x512 bf16)
  bf16_t* H   = R4;                 // 50331648 = 8192x6144 (R4+R5+R6 contiguous)

  const dim3 blk(256), blk8(512), tb(32, 8);
  const float scl = 0.025515518153991442f;  // 1/sqrt(1536)

  auto T = [&](const float* W, bf16_t* Wt, int K, int N, const float* s, int ldt) {
    transpose_to_bf16<<<dim3(N / 32, K / 32), tb, 0, stream>>>(W, Wt, K, N, s, ldt);
  };
  auto g8 = [](int M, int N) { return dim3(N / 256, M / 256); };
  auto g4 = [](int M, int N) { return dim3(N / 128, M / 128); };

  // biases
  hipMemcpyAsync(biascat, bq, DD * sizeof(float), hipMemcpyDeviceToDevice, stream);
  hipMemcpyAsync(biascat + DD, bk, DD * sizeof(float), hipMemcpyDeviceToDevice, stream);
  bias_add2<<<6, blk, 0, stream>>>(bo, Cbo, biasm, DD);

  // norms for x
  norm_x2<<<8192, blk, 0, stream>>>(x, R2 /*xr*/, R4 /*xb*/);

  // V projection (raw x) -> V^T batched
  T(Wv, R0, DD, DD, nullptr, DD);
  gemm8<EPI_TRANS><<<g8(8192, DD), blk8, 0, stream>>>(R4 /*xb*/, R0, bv, R5, nullptr,
      24, DD, DD, 0, 1.f, 0, 0, 4096, 12, (size_t)DD * 4096);

  // merged Q|K projection + CQ projection (rms weights folded into W^T)
  T(Wq, R1, DD, DD, sqw, DD);
  T(Wk, R1 + 2359296, DD, DD, skw, DD);
  T(CWq, R1 + 4718592, DD, DD, cqw, DD);
  gemm8<EPI_BF16><<<g8(8192, 3072), blk8, 0, stream>>>(R2, R1, biascat, R4, nullptr,
      24, DD, DD, 3072, 1.f, 0, 0, 0, 0, 0);
  gemm8<EPI_BF16><<<g8(8192, DD), blk8, 0, stream>>>(R2, R1 + 4718592, Cbq, R6, nullptr,
      24, DD, DD, DD, 1.f, 0, 0, 0, 0, 0);

  // self-attention (batched over 2 via m0>>12)
  gemm8<EPI_BF16S><<<g8(8192, 4096), blk8, 0, stream>>>(R4 /*Q*/, R4 + DD /*K*/, nullptr, S, nullptr,
      24, 3072, 3072, 4096, scl, 12, (size_t)4096 * 3072, 0, 0, 0);
  softmax_bf16<4096><<<8192, blk, 0, stream>>>(S);
  // PV -> concat cols 0-1535 (Q,K dead)
  gemm8<EPI_BF16><<<g8(8192, DD), blk8, 0, stream>>>(S, R5, nullptr, R4, nullptr,
      64, 4096, 4096, 3072, 1.f, 12, (size_t)DD * 4096, 0, 0, 0);

  // cross-attention (S region dead)
  norm_t2<<<1024, blk, 0, stream>>>(te, Tb, Tck);
  T(CWk, R1, DD, DD, ckw, DD);
  gemm_bt<EPI_BF16><<<g4(1024, DD), blk, 0, stream>>>(Tck, R1, Cbk, CK, nullptr,
      48, DD, DD, DD, 1.f, 0, 0, 0, 0, 0);
  T(CWv, R1 + 2359296, DD, DD, nullptr, DD);
  gemm_bt<EPI_TRANS><<<g4(1024, DD), blk, 0, stream>>>(Tb, R1 + 2359296, Cbv, CVt, nullptr,
      48, DD, DD, 0, 1.f, 0, 0, 512, 9, (size_t)DD * 512);
  gemm_bt<EPI_BF16S><<<g4(8192, 512), blk, 0, stream>>>(R6 /*CQ*/, CK, nullptr, Sc, nullptr,
      48, DD, DD, 512, scl, 12, (size_t)512 * DD, 0, 0, 0);
  softmax_bf16<512><<<8192, blk, 0, stream>>>(Sc);
  // cross-PV -> concat cols 1536-3071 (CQ dead)
  gemm8<EPI_BF16><<<g8(8192, DD), blk8, 0, stream>>>(Sc, CVt, nullptr, R4 + 1536, nullptr,
      8, 512, 512, 3072, 1.f, 12, (size_t)DD * 512, 0, 0, 0);

  // merged out = x + concat @ [Wo;CWo] + (bo+Cbo)
  T(Wo, R1, DD, DD, nullptr, 3072);
  T(CWo, R1 + 1536, DD, DD, nullptr, 3072);
  gemm8<EPI_ADD_X><<<g8(8192, DD), blk8, 0, stream>>>(R4, R1, biasm, out, x,
      48, 3072, 3072, DD, 1.f, 0, 0, 0, 0, 0);

  // FFN: LN -> W1+gelu (single N=6144) -> W2 (single K=6144) acc
  norm_ln<<<8192, blk, 0, stream>>>(x, lnw, lnb, R2);
  T(W1, R0, DD, FF, nullptr, DD);
  gemm8<EPI_GELU><<<g8(8192, FF), blk8, 0, stream>>>(R2, R0, b1, H, nullptr,
      24, DD, DD, FF, 1.f, 0, 0, 0, 0, 0);
  T(W2, R1, FF, DD, nullptr, FF);
  gemm8<EPI_ACC><<<g8(8192, DD), blk8, 0, stream>>>(H, R1, b2, out, nullptr,
      96, FF, FF, DD, 1.f, 0, 0, 0, 0, 0);
}

// Round 9
// 1212.827 us; speedup vs baseline: 1.2064x; 1.1099x over previous
//
#include <hip/hip_runtime.h>
#include <hip/hip_bf16.h>
#include <cmath>

#define DD 1536
#define FF 6144

typedef __bf16 bf16_t;
typedef __bf16 bf16x8 __attribute__((ext_vector_type(8)));
typedef __bf16 bf16x4 __attribute__((ext_vector_type(4)));
typedef float  f32x4  __attribute__((ext_vector_type(4)));

#define VM6 asm volatile("s_waitcnt vmcnt(6)" ::: "memory")
#define VM0 asm volatile("s_waitcnt vmcnt(0)" ::: "memory")
#define LGKM0 do { asm volatile("s_waitcnt lgkmcnt(0)" :::); __builtin_amdgcn_sched_barrier(0); } while (0)
#define BAR __builtin_amdgcn_s_barrier()

__device__ __forceinline__ void async_load16(const bf16_t* g, bf16_t* l) {
  __builtin_amdgcn_global_load_lds(
      (const __attribute__((address_space(1))) void*)g,
      (__attribute__((address_space(3))) void*)l, 16, 0, 0);
}

// inline-asm LDS read: NOT ordered vs global_load_lds by the compiler; ordering is
// done explicitly via {vmcnt; barrier} (RAW) and {lgkmcnt(0); sched_barrier} (use).
__device__ __forceinline__ bf16x8 ds_read128(unsigned int addr) {
  bf16x8 r;
  asm volatile("ds_read_b128 %0, %1" : "=v"(r) : "v"(addr));
  return r;
}

// bijective XCD-aware remap (m204)
__device__ __forceinline__ void xcd_remap(int& bx, int& by) {
  const int gx = gridDim.x, gy = gridDim.y;
  int wg = by * gx + bx;
  const int nwg = gx * gy;
  const int q = nwg >> 3, r = nwg & 7, xcd = wg & 7, o = wg >> 3;
  wg = (xcd < r ? xcd * (q + 1) : r * (q + 1) + (xcd - r) * q) + o;
  bx = wg % gx;
  by = wg / gx;
}

// ---------------- weight fp32 -> bf16 transpose; optional per-K scale; output row stride ldt
__global__ __launch_bounds__(256) void transpose_to_bf16(
    const float* __restrict__ W, bf16_t* __restrict__ Wt, int K, int N,
    const float* __restrict__ s, int ldt) {
  __shared__ float tile[32][33];
  const int tx = threadIdx.x, ty = threadIdx.y;  // 32 x 8
  const int n0 = blockIdx.x * 32, k0 = blockIdx.y * 32;
#pragma unroll
  for (int i = 0; i < 4; i++)
    tile[ty + 8 * i][tx] = W[(size_t)(k0 + ty + 8 * i) * N + n0 + tx];
  __syncthreads();
  const float sc = (s != nullptr) ? s[k0 + tx] : 1.f;
#pragma unroll
  for (int i = 0; i < 4; i++)
    Wt[(size_t)(n0 + ty + 8 * i) * ldt + k0 + tx] = (bf16_t)(tile[tx][ty + 8 * i] * sc);
}

// ---------------- biasm = a + b ----------------
__global__ __launch_bounds__(256) void bias_add2(
    const float* __restrict__ a, const float* __restrict__ b, float* __restrict__ o, int n) {
  const int i = blockIdx.x * 256 + threadIdx.x;
  if (i < n) o[i] = a[i] + b[i];
}

// ---------------- reduction helpers ----------------
__device__ __forceinline__ void breduce1(float& a) {
#pragma unroll
  for (int off = 32; off; off >>= 1) a += __shfl_xor(a, off);
  __shared__ float sa[4];
  const int w = threadIdx.x >> 6, ln = threadIdx.x & 63;
  if (ln == 0) sa[w] = a;
  __syncthreads();
  a = (sa[0] + sa[1]) + (sa[2] + sa[3]);
  __syncthreads();
}

__device__ __forceinline__ void breduce2(float& a, float& b) {
#pragma unroll
  for (int off = 32; off; off >>= 1) {
    a += __shfl_xor(a, off);
    b += __shfl_xor(b, off);
  }
  __shared__ float sa[4], sb[4];
  const int w = threadIdx.x >> 6, ln = threadIdx.x & 63;
  if (ln == 0) { sa[w] = a; sb[w] = b; }
  __syncthreads();
  a = (sa[0] + sa[1]) + (sa[2] + sa[3]);
  b = (sb[0] + sb[1]) + (sb[2] + sb[3]);
  __syncthreads();
}

// ---------------- x: shared rms factor -> xr = x*rq (bf16), xb = x (bf16) ----------------
__global__ __launch_bounds__(256) void norm_x2(
    const float* __restrict__ x, bf16_t* __restrict__ xr, bf16_t* __restrict__ xb) {
  const int row = blockIdx.x, t = threadIdx.x;
  const float* p = x + (size_t)row * DD;
  f32x4 v0 = ((const f32x4*)p)[t];
  f32x4 v1 = 0.0f;
  if (t < 128) v1 = ((const f32x4*)p)[256 + t];
  float s2 = 0.f;
#pragma unroll
  for (int e = 0; e < 4; e++) s2 += v0[e] * v0[e];
  if (t < 128) {
#pragma unroll
    for (int e = 0; e < 4; e++) s2 += v1[e] * v1[e];
  }
  breduce1(s2);
  const float rq = rsqrtf(s2 * (1.f / DD) + 1e-7f);
  auto emit = [&](int ci, f32x4 v) {
    bf16x4 orr, ob;
#pragma unroll
    for (int e = 0; e < 4; e++) {
      orr[e] = (bf16_t)(v[e] * rq);
      ob[e] = (bf16_t)v[e];
    }
    const size_t o = (size_t)row * DD + ci * 4;
    *(bf16x4*)(xr + o) = orr;
    *(bf16x4*)(xb + o) = ob;
  };
  emit(t, v0);
  if (t < 128) emit(256 + t, v1);
}

// ---------------- LayerNorm -> bf16 ----------------
__global__ __launch_bounds__(256) void norm_ln(
    const float* __restrict__ x, const float* __restrict__ w,
    const float* __restrict__ bb, bf16_t* __restrict__ o) {
  const int row = blockIdx.x, t = threadIdx.x;
  const float* p = x + (size_t)row * DD;
  f32x4 v0 = ((const f32x4*)p)[t];
  f32x4 v1 = 0.0f;
  if (t < 128) v1 = ((const f32x4*)p)[256 + t];
  float s = 0.f, s2 = 0.f;
#pragma unroll
  for (int e = 0; e < 4; e++) { s += v0[e]; s2 += v0[e] * v0[e]; }
  if (t < 128) {
#pragma unroll
    for (int e = 0; e < 4; e++) { s += v1[e]; s2 += v1[e] * v1[e]; }
  }
  breduce2(s, s2);
  const float mu = s * (1.f / DD);
  const float rln = rsqrtf(s2 * (1.f / DD) - mu * mu + 1e-5f);
  auto emit = [&](int ci, f32x4 v) {
    const int i0 = ci * 4;
    bf16x4 ov;
#pragma unroll
    for (int e = 0; e < 4; e++)
      ov[e] = (bf16_t)((v[e] - mu) * rln * w[i0 + e] + bb[i0 + e]);
    *(bf16x4*)(o + (size_t)row * DD + i0) = ov;
  };
  emit(t, v0);
  if (t < 128) emit(256 + t, v1);
}

// ---------------- text: Tb = raw bf16, Tck = text*rtq ----------
__global__ __launch_bounds__(256) void norm_t2(
    const float* __restrict__ te, bf16_t* __restrict__ tb, bf16_t* __restrict__ tck) {
  const int row = blockIdx.x, t = threadIdx.x;
  const float* p = te + (size_t)row * DD;
  f32x4 v0 = ((const f32x4*)p)[t];
  f32x4 v1 = 0.0f;
  if (t < 128) v1 = ((const f32x4*)p)[256 + t];
  float s2 = 0.f;
#pragma unroll
  for (int e = 0; e < 4; e++) s2 += v0[e] * v0[e];
  if (t < 128) {
#pragma unroll
    for (int e = 0; e < 4; e++) s2 += v1[e] * v1[e];
  }
  breduce1(s2);
  const float rq = rsqrtf(s2 * (1.f / DD) + 1e-7f);
  auto emit = [&](int ci, f32x4 v) {
    bf16x4 ob, oc;
#pragma unroll
    for (int e = 0; e < 4; e++) {
      ob[e] = (bf16_t)v[e];
      oc[e] = (bf16_t)(v[e] * rq);
    }
    const size_t o = (size_t)row * DD + ci * 4;
    *(bf16x4*)(tb + o) = ob;
    *(bf16x4*)(tck + o) = oc;
  };
  emit(t, v0);
  if (t < 128) emit(256 + t, v1);
}

// ---------------- in-place bf16 row softmax ----------------
template <int NC>
__global__ __launch_bounds__(256) void softmax_bf16(bf16_t* __restrict__ S) {
  const int t = threadIdx.x;
  bf16_t* sr = S + (size_t)blockIdx.x * NC;
  constexpr int NV = (NC / 8 + 255) / 256;
  float v[NV][8];
  float mx = -3.4e38f;
#pragma unroll
  for (int i = 0; i < NV; i++) {
    const int idx = t + i * 256;
    if (idx * 8 < NC) {
      bf16x8 b = ((const bf16x8*)sr)[idx];
#pragma unroll
      for (int e = 0; e < 8; e++) {
        v[i][e] = (float)b[e];
        mx = fmaxf(mx, v[i][e]);
      }
    }
  }
#pragma unroll
  for (int off = 32; off; off >>= 1) mx = fmaxf(mx, __shfl_xor(mx, off));
  __shared__ float sm[4];
  const int w = t >> 6, ln = t & 63;
  if (ln == 0) sm[w] = mx;
  __syncthreads();
  mx = fmaxf(fmaxf(sm[0], sm[1]), fmaxf(sm[2], sm[3]));
  __syncthreads();
  float sum = 0.f;
#pragma unroll
  for (int i = 0; i < NV; i++) {
    const int idx = t + i * 256;
    if (idx * 8 < NC) {
#pragma unroll
      for (int e = 0; e < 8; e++) {
        v[i][e] = __expf(v[i][e] - mx);
        sum += v[i][e];
      }
    }
  }
#pragma unroll
  for (int off = 32; off; off >>= 1) sum += __shfl_xor(sum, off);
  __shared__ float ss[4];
  if (ln == 0) ss[w] = sum;
  __syncthreads();
  sum = (ss[0] + ss[1]) + (ss[2] + ss[3]);
  const float inv = 1.f / sum;
#pragma unroll
  for (int i = 0; i < NV; i++) {
    const int idx = t + i * 256;
    if (idx * 8 < NC) {
      bf16x8 o;
#pragma unroll
      for (int e = 0; e < 8; e++) o[e] = (bf16_t)(v[i][e] * inv);
      ((bf16x8*)sr)[idx] = o;
    }
  }
}

enum { EPI_BF16 = 0, EPI_F32_SCALE = 1, EPI_ADD_X = 2, EPI_ACC = 3, EPI_GELU = 4, EPI_TRANS = 5, EPI_BF16S = 6 };

template <int EPI>
__device__ __forceinline__ void epi_frag(
    f32x4 v, int r0, int c, const float* bias, void* Cout, const float* Xres,
    int ldc, float scale, int t_ld, int t_bshift, size_t t_bstride) {
  const float bv = (bias != nullptr) ? bias[c] : 0.f;
  if constexpr (EPI == EPI_BF16) {
    bf16_t* C = (bf16_t*)Cout;
#pragma unroll
    for (int r = 0; r < 4; r++) C[(size_t)(r0 + r) * ldc + c] = (bf16_t)(v[r] + bv);
  } else if constexpr (EPI == EPI_F32_SCALE) {
    float* C = (float*)Cout;
#pragma unroll
    for (int r = 0; r < 4; r++) C[(size_t)(r0 + r) * ldc + c] = v[r] * scale;
  } else if constexpr (EPI == EPI_BF16S) {
    bf16_t* C = (bf16_t*)Cout;
#pragma unroll
    for (int r = 0; r < 4; r++) C[(size_t)(r0 + r) * ldc + c] = (bf16_t)(v[r] * scale);
  } else if constexpr (EPI == EPI_ADD_X) {
    float* C = (float*)Cout;
#pragma unroll
    for (int r = 0; r < 4; r++) {
      const size_t ix = (size_t)(r0 + r) * ldc + c;
      C[ix] = Xres[ix] + v[r] + bv;
    }
  } else if constexpr (EPI == EPI_ACC) {
    float* C = (float*)Cout;
#pragma unroll
    for (int r = 0; r < 4; r++) {
      const size_t ix = (size_t)(r0 + r) * ldc + c;
      C[ix] += v[r] + bv;
    }
  } else if constexpr (EPI == EPI_GELU) {
    bf16_t* C = (bf16_t*)Cout;
#pragma unroll
    for (int r = 0; r < 4; r++) {
      const float h = v[r] + bv;
      C[(size_t)(r0 + r) * ldc + c] = (bf16_t)(0.5f * h * (1.f + erff(h * 0.70710678118654752f)));
    }
  } else {  // EPI_TRANS: batched C^T: out[b][c][n]
    const int b = r0 >> t_bshift;
    const int n = r0 & ((1 << t_bshift) - 1);
    bf16_t* C = (bf16_t*)Cout + (size_t)b * t_bstride + (size_t)c * t_ld + n;
    bf16x4 o;
#pragma unroll
    for (int r = 0; r < 4; r++) o[r] = (bf16_t)(v[r] + bv);
    *(bf16x4*)C = o;
  }
}

// ---------------- gemm_bt: 128x128 tile, 4 waves, BK=32 (proven r2 kernel + batch-B) ------
template <int EPI>
__global__ __launch_bounds__(256) void gemm_bt(
    const bf16_t* __restrict__ A, const bf16_t* __restrict__ B,
    const float* __restrict__ bias, void* __restrict__ Cout,
    const float* __restrict__ Xres,
    int nK, int lda, int ldb, int ldc, float scale,
    int bsh, size_t bstr, int t_ld, int t_bshift, size_t t_bstride) {
  __shared__ __align__(16) bf16_t As[2][128 * 32];
  __shared__ __align__(16) bf16_t Bs[2][128 * 32];
  const int tid = threadIdx.x;
  int bx = blockIdx.x, by = blockIdx.y;
  xcd_remap(bx, by);
  const int m0 = by * 128, n0 = bx * 128;
  const int wave = tid >> 6, lane = tid & 63, l15 = lane & 15, hi = lane >> 4;
  const int wm = wave >> 1, wn = wave & 1;
  const int srow = tid >> 2, scol = (tid & 3) << 3;

  const bf16_t* Bb = bsh ? (B + (size_t)(m0 >> bsh) * bstr) : B;
  const bf16_t* ga = A + (size_t)(m0 + srow) * lda + scol;
  const bf16_t* gb = Bb + (size_t)(n0 + srow) * ldb + scol;
  const int lo = wave * 512;

  f32x4 acc[4][4];
#pragma unroll
  for (int i = 0; i < 4; i++)
#pragma unroll
    for (int j = 0; j < 4; j++) acc[i][j] = 0.0f;

  auto stage = [&](int buf, int kt) {
    const bf16_t* a = ga + (size_t)kt * 32;
    const bf16_t* b = gb + (size_t)kt * 32;
    async_load16(a, &As[buf][lo]);
    async_load16(a + (size_t)64 * lda, &As[buf][2048 + lo]);
    async_load16(b, &Bs[buf][lo]);
    async_load16(b + (size_t)64 * ldb, &Bs[buf][2048 + lo]);
  };

  auto compute = [&](int buf) {
    bf16x8 af[4], bg[4];
#pragma unroll
    for (int i = 0; i < 4; i++)
      af[i] = *(const bf16x8*)&As[buf][(wm * 64 + i * 16 + l15) * 32 + hi * 8];
#pragma unroll
    for (int j = 0; j < 4; j++)
      bg[j] = *(const bf16x8*)&Bs[buf][(wn * 64 + j * 16 + l15) * 32 + hi * 8];
#pragma unroll
    for (int i = 0; i < 4; i++)
#pragma unroll
      for (int j = 0; j < 4; j++)
        acc[i][j] = __builtin_amdgcn_mfma_f32_16x16x32_bf16(af[i], bg[j], acc[i][j], 0, 0, 0);
  };

  stage(0, 0);
  __syncthreads();
  for (int kt = 0; kt < nK; ++kt) {
    if (kt + 1 < nK) stage((kt + 1) & 1, kt + 1);
    compute(kt & 1);
    __syncthreads();
  }

#pragma unroll
  for (int i = 0; i < 4; i++) {
    const int r0 = m0 + wm * 64 + i * 16 + hi * 4;
#pragma unroll
    for (int j = 0; j < 4; j++) {
      const int c = n0 + wn * 64 + j * 16 + l15;
      epi_frag<EPI>(acc[i][j], r0, c, bias, Cout, Xres, ldc, scale, t_ld, t_bshift, t_bstride);
    }
  }
}

// ---------------- gemm8: 256x256 tile, 8 waves, BK=64, 8-phase, asm ds_read ----------
// RAW (global->LDS->read): tile k confirmed at q3(k-1)'s {VM6; BAR} (the 6 newest loads
// there are {Bl,Bh,Al}(k+1-staged-for-k+2 slots); everything through Ah(k) drained).
// ds_reads are inline asm (NOT compiler-ordered vs global_load_lds); their consumption
// is fenced by {BAR; s_waitcnt lgkmcnt(0); sched_barrier(0)} before each MFMA cluster
// (rule #18). WAR: B[buf] reads retire by q1's LGKM0+MM+BAR -> stgB(k+2)@q2 safe;
// A[buf] reads retire by q2's -> stgA(k+2)@q3 safe; As[buf^1] write @q0 is 2 barriers
// past its last reader (iteration k-1 q2).
template <int EPI>
__global__ __launch_bounds__(512, 2) void gemm8(
    const bf16_t* __restrict__ A, const bf16_t* __restrict__ B,
    const float* __restrict__ bias, void* __restrict__ Cout,
    const float* __restrict__ Xres,
    int nT, int lda, int ldb, int ldc, float scale,
    int bsh, size_t bstr, int t_ld, int t_bshift, size_t t_bstride) {
  __shared__ __align__(16) bf16_t As[2][256 * 64];
  __shared__ __align__(16) bf16_t Bs[2][256 * 64];
  const int tid = threadIdx.x;
  int bx = blockIdx.x, by = blockIdx.y;
  xcd_remap(bx, by);
  const int m0 = by * 256, n0 = bx * 256;
  const int wave = tid >> 6, lane = tid & 63, l15 = lane & 15, hi = lane >> 4;
  const int wm = wave >> 2, wn = wave & 3;  // 2 x 4 waves; per-wave 128x64 output

  const int srow = tid >> 3;
  const int scol = ((tid & 7) ^ (srow & 7)) << 3;
  const bf16_t* Bb = bsh ? (B + (size_t)(m0 >> bsh) * bstr) : B;
  const bf16_t* gA = A + (size_t)(m0 + srow) * lda + scol;
  const bf16_t* gB = Bb + (size_t)(n0 + srow) * ldb + scol;
  const int ldst = wave * 512;

  f32x4 acc[8][4];
#pragma unroll
  for (int i = 0; i < 8; i++)
#pragma unroll
    for (int j = 0; j < 4; j++) acc[i][j] = 0.0f;

  auto stgA = [&](int t, int half) {
    if (t >= nT) return;
    const int buf = t & 1, r0 = half << 7;
    const size_t kof = (size_t)t * 64;
    async_load16(gA + (size_t)r0 * lda + kof, &As[buf][r0 * 64 + ldst]);
    async_load16(gA + (size_t)(r0 + 64) * lda + kof, &As[buf][(r0 + 64) * 64 + ldst]);
  };
  auto stgB = [&](int t, int half) {
    if (t >= nT) return;
    const int buf = t & 1, r0 = half << 7;
    const size_t kof = (size_t)t * 64;
    async_load16(gB + (size_t)r0 * ldb + kof, &Bs[buf][r0 * 64 + ldst]);
    async_load16(gB + (size_t)(r0 + 64) * ldb + kof, &Bs[buf][(r0 + 64) * 64 + ldst]);
  };

  bf16x8 af[4][2], bg[2][2][2];
  auto LDA = [&](int buf, int mh) {
#pragma unroll
    for (int i = 0; i < 4; i++) {
      const int r = wm * 128 + (mh * 4 + i) * 16 + l15;
      const int rx = r & 7;
#pragma unroll
      for (int ks = 0; ks < 2; ks++)
        af[i][ks] = ds_read128((unsigned int)(size_t)&As[buf][r * 64 + (((hi + 4 * ks) ^ rx) << 3)]);
    }
  };
  auto LDB = [&](int buf, int nh) {
#pragma unroll
    for (int j = 0; j < 2; j++) {
      const int r = wn * 64 + (nh * 2 + j) * 16 + l15;
      const int rx = r & 7;
#pragma unroll
      for (int ks = 0; ks < 2; ks++)
        bg[nh][j][ks] = ds_read128((unsigned int)(size_t)&Bs[buf][r * 64 + (((hi + 4 * ks) ^ rx) << 3)]);
    }
  };
  auto MM = [&](int mh, int nh) {
    __builtin_amdgcn_s_setprio(1);
#pragma unroll
    for (int i = 0; i < 4; i++)
#pragma unroll
      for (int j = 0; j < 2; j++)
#pragma unroll
        for (int ks = 0; ks < 2; ks++)
          acc[mh * 4 + i][nh * 2 + j] = __builtin_amdgcn_mfma_f32_16x16x32_bf16(
              af[i][ks], bg[nh][j][ks], acc[mh * 4 + i][nh * 2 + j], 0, 0, 0);
    __builtin_amdgcn_s_setprio(0);
  };

  // prologue: tile0 fully + tile1 {Bl,Bh,Al}; confirm tile 0 (6 newer loads in flight)
  stgB(0, 0); stgB(0, 1); stgA(0, 0); stgA(0, 1);
  stgB(1, 0); stgB(1, 1); stgA(1, 0);
  if (nT > 1) { VM6; } else { VM0; }
  BAR;

  for (int k = 0; k < nT; ++k) {
    const int buf = k & 1;
    // q0: stage Ah(k+1); reads (tile k, confirmed last iter) pre-barrier
    stgA(k + 1, 1);
    LDA(buf, 0);
    LDB(buf, 0);
    BAR;
    LGKM0;
    MM(0, 0);
    BAR;
    // q1: read bg(nh1); B[buf] fully consumed after this phase
    LDB(buf, 1);
    BAR;
    LGKM0;
    MM(0, 1);
    BAR;
    // q2: stage Bl(k+2); read af(mh1); A[buf] fully consumed after this phase
    stgB(k + 2, 0);
    LDA(buf, 1);
    BAR;
    LGKM0;
    MM(1, 0);
    BAR;
    // q3: stage Bh,Al(k+2); confirm tile k+1 (counted; VM0 on tail)
    stgB(k + 2, 1);
    stgA(k + 2, 0);
    if (k + 2 < nT) { VM6; } else { VM0; }
    BAR;
    MM(1, 1);
    BAR;
  }

#pragma unroll
  for (int fi = 0; fi < 8; fi++) {
    const int r0 = m0 + wm * 128 + fi * 16 + hi * 4;
#pragma unroll
    for (int fj = 0; fj < 4; fj++) {
      const int c = n0 + wn * 64 + fj * 16 + l15;
      epi_frag<EPI>(acc[fi][fj], r0, c, bias, Cout, Xres, ldc, scale, t_ld, t_bshift, t_bstride);
    }
  }
}

// ---------------- host ----------------
extern "C" void kernel_launch(void* const* d_in, const int* in_sizes, int n_in,
                              void* d_out, int out_size, void* d_ws, size_t ws_size,
                              hipStream_t stream) {
  (void)in_sizes; (void)n_in; (void)out_size; (void)ws_size;
  const float* x   = (const float*)d_in[0];
  const float* te  = (const float*)d_in[1];
  const float* sqw = (const float*)d_in[2];
  const float* skw = (const float*)d_in[3];
  const float* cqw = (const float*)d_in[4];
  const float* ckw = (const float*)d_in[5];
  const float* lnw = (const float*)d_in[6];
  const float* lnb = (const float*)d_in[7];
  const float* Wq = (const float*)d_in[8];  const float* bq = (const float*)d_in[9];
  const float* Wk = (const float*)d_in[10]; const float* bk = (const float*)d_in[11];
  const float* Wv = (const float*)d_in[12]; const float* bv = (const float*)d_in[13];
  const float* Wo = (const float*)d_in[14]; const float* bo = (const float*)d_in[15];
  const float* CWq = (const float*)d_in[16]; const float* Cbq = (const float*)d_in[17];
  const float* CWk = (const float*)d_in[18]; const float* Cbk = (const float*)d_in[19];
  const float* CWv = (const float*)d_in[20]; const float* Cbv = (const float*)d_in[21];
  const float* CWo = (const float*)d_in[22]; const float* Cbo = (const float*)d_in[23];
  const float* W1 = (const float*)d_in[24]; const float* b1 = (const float*)d_in[25];
  const float* W2 = (const float*)d_in[26]; const float* b2 = (const float*)d_in[27];
  float* out = (float*)d_out;

  // ---- arena (bf16 el offsets); peak ~170 MB ----
  bf16_t* ws = (bf16_t*)d_ws;
  bf16_t* R0 = ws;                  // 9437184: Wv^T -> {CK,CVt,Sc} -> W1^T
  bf16_t* R1 = ws + 9437184;        // 9437184: Wq|Wk|CWq^T -> CWk/CWv^T -> WTm -> W2^T
  bf16_t* R2 = ws + 18874368;       // 12582912: xr -> LNo
  bf16_t* Tb  = ws + 31457280;      // 1572864
  bf16_t* Tck = ws + 33030144;      // 1572864
  bf16_t* R4 = ws + 34603008;       // 25165824: xb -> Q|K(ldc3072) -> concat APre|CPre -> H[0:..]
  bf16_t* R5 = ws + 59768832;       // 12582912: V^T -> H mid
  bf16_t* R6 = ws + 72351744;       // 12582912: CQ -> H end
  bf16_t* S  = ws;                  // 33554432 overlay (self-attn scores)
  float* biascat = (float*)(ws + 84934656);  // 3072 f32
  float* biasm   = (float*)(ws + 84940800);  // 1536 f32
  bf16_t* CK  = R0;
  bf16_t* CVt = R0 + 1572864;
  bf16_t* Sc  = R0 + 3145728;       // 8192x512 bf16
  bf16_t* H   = R4;                 // 8192x6144 (R4+R5+R6 contiguous)

  const dim3 blk(256), blk8(512), tb(32, 8);
  const float scl = 0.025515518153991442f;  // 1/sqrt(1536)

  auto T = [&](const float* W, bf16_t* Wt, int K, int N, const float* s, int ldt) {
    transpose_to_bf16<<<dim3(N / 32, K / 32), tb, 0, stream>>>(W, Wt, K, N, s, ldt);
  };
  auto g8 = [](int M, int N) { return dim3(N / 256, M / 256); };
  auto g4 = [](int M, int N) { return dim3(N / 128, M / 128); };

  // biases
  hipMemcpyAsync(biascat, bq, DD * sizeof(float), hipMemcpyDeviceToDevice, stream);
  hipMemcpyAsync(biascat + DD, bk, DD * sizeof(float), hipMemcpyDeviceToDevice, stream);
  bias_add2<<<6, blk, 0, stream>>>(bo, Cbo, biasm, DD);

  // norms for x
  norm_x2<<<8192, blk, 0, stream>>>(x, R2 /*xr*/, R4 /*xb*/);

  // V projection (raw x) -> V^T batched
  T(Wv, R0, DD, DD, nullptr, DD);
  gemm8<EPI_TRANS><<<g8(8192, DD), blk8, 0, stream>>>(R4 /*xb*/, R0, bv, R5, nullptr,
      24, DD, DD, 0, 1.f, 0, 0, 4096, 12, (size_t)DD * 4096);

  // merged Q|K projection + CQ projection (rms weights folded into W^T)
  T(Wq, R1, DD, DD, sqw, DD);
  T(Wk, R1 + 2359296, DD, DD, skw, DD);
  T(CWq, R1 + 4718592, DD, DD, cqw, DD);
  gemm8<EPI_BF16><<<g8(8192, 3072), blk8, 0, stream>>>(R2, R1, biascat, R4, nullptr,
      24, DD, DD, 3072, 1.f, 0, 0, 0, 0, 0);
  gemm8<EPI_BF16><<<g8(8192, DD), blk8, 0, stream>>>(R2, R1 + 4718592, Cbq, R6, nullptr,
      24, DD, DD, DD, 1.f, 0, 0, 0, 0, 0);

  // self-attention (batched over 2 via m0>>12)
  gemm8<EPI_BF16S><<<g8(8192, 4096), blk8, 0, stream>>>(R4 /*Q*/, R4 + DD /*K*/, nullptr, S, nullptr,
      24, 3072, 3072, 4096, scl, 12, (size_t)4096 * 3072, 0, 0, 0);
  softmax_bf16<4096><<<8192, blk, 0, stream>>>(S);
  gemm8<EPI_BF16><<<g8(8192, DD), blk8, 0, stream>>>(S, R5, nullptr, R4, nullptr,
      64, 4096, 4096, 3072, 1.f, 12, (size_t)DD * 4096, 0, 0, 0);

  // cross-attention
  norm_t2<<<1024, blk, 0, stream>>>(te, Tb, Tck);
  T(CWk, R1, DD, DD, ckw, DD);
  gemm_bt<EPI_BF16><<<g4(1024, DD), blk, 0, stream>>>(Tck, R1, Cbk, CK, nullptr,
      48, DD, DD, DD, 1.f, 0, 0, 0, 0, 0);
  T(CWv, R1 + 2359296, DD, DD, nullptr, DD);
  gemm_bt<EPI_TRANS><<<g4(1024, DD), blk, 0, stream>>>(Tb, R1 + 2359296, Cbv, CVt, nullptr,
      48, DD, DD, 0, 1.f, 0, 0, 512, 9, (size_t)DD * 512);
  gemm_bt<EPI_BF16S><<<g4(8192, 512), blk, 0, stream>>>(R6 /*CQ*/, CK, nullptr, Sc, nullptr,
      48, DD, DD, 512, scl, 12, (size_t)512 * DD, 0, 0, 0);
  softmax_bf16<512><<<8192, blk, 0, stream>>>(Sc);
  gemm8<EPI_BF16><<<g8(8192, DD), blk8, 0, stream>>>(Sc, CVt, nullptr, R4 + 1536, nullptr,
      8, 512, 512, 3072, 1.f, 12, (size_t)DD * 512, 0, 0, 0);

  // merged out = x + concat @ [Wo;CWo] + (bo+Cbo)
  T(Wo, R1, DD, DD, nullptr, 3072);
  T(CWo, R1 + 1536, DD, DD, nullptr, 3072);
  gemm8<EPI_ADD_X><<<g8(8192, DD), blk8, 0, stream>>>(R4, R1, biasm, out, x,
      48, 3072, 3072, DD, 1.f, 0, 0, 0, 0, 0);

  // FFN: LN -> W1+gelu (single N=6144) -> W2 (single K=6144) acc
  norm_ln<<<8192, blk, 0, stream>>>(x, lnw, lnb, R2);
  T(W1, R0, DD, FF, nullptr, DD);
  gemm8<EPI_GELU><<<g8(8192, FF), blk8, 0, stream>>>(R2, R0, b1, H, nullptr,
      24, DD, DD, FF, 1.f, 0, 0, 0, 0, 0);
  T(W2, R1, FF, DD, nullptr, FF);
  gemm8<EPI_ACC><<<g8(8192, DD), blk8, 0, stream>>>(H, R1, b2, out, nullptr,
      96, FF, FF, DD, 1.f, 0, 0, 0, 0, 0);
}